// Round 3
// baseline (383.919 us; speedup 1.0000x reference)
//
#include <hip/hip_runtime.h>
#include <hip/hip_bf16.h>
#include <math.h>

// x (2,128,512,512) f32.
//   s = sum_c x ; edge = sum_k |conv3x3(s, sobel_k)| ; out = maxpool2x2(edge)
//   broadcast over all 128 channels.  HBM floor: 256MB rd + 64MB wr ~= 51us.
//
// Pipeline (3 graph nodes):
//   memset : zero padded s-plane (2.1 MB)  (~0.4us)
//   k1     : 128-channel sum -> zero-padded s plane (256MB rd, 2MB wr, ~43us)
//   k2     : branchless sobel+|.|+2x2maxpool, broadcast 64MB wr (~12us)

#define N 2
#define C 128
#define H 512
#define W 512
#define HW (H * W)
#define PH 256
#define PW 256
#define PHW (PH * PW)

#define NHW4 (N * HW / 4)          // 131072 float4 sites
#define SW 520                     // padded row stride (floats) -> 16B aligned
#define SR 514                     // padded rows (1 top + 512 + 1 bottom)
#define SPLANE (SR * SW)           // floats per padded plane

// ------------- k1: full channel sum, write into padded plane ---------------
// 512 blocks x 256 thr = 8 waves/CU. 4 independent accumulators over channel
// quarters -> 32 independent in-flight loads per unroll step (512B/thread).
__global__ void __launch_bounds__(256) ksum_pad(const float* __restrict__ x,
                                                float* __restrict__ spad) {
    int idx = blockIdx.x * blockDim.x + threadIdx.x;   // 0 .. NHW4-1
    int n   = idx >> 16;                               // /65536 (HW/4)
    int sp  = idx & 65535;
    const float4* xp = (const float4*)(x + (size_t)n * C * HW) + sp;
    const int cs = HW / 4;                             // channel stride (float4)

    float4 a0 = make_float4(0.f, 0.f, 0.f, 0.f);
    float4 a1 = a0, a2 = a0, a3 = a0;
#pragma unroll 8
    for (int c = 0; c < 32; ++c) {
        float4 v0 = xp[(size_t)(c      ) * cs];
        float4 v1 = xp[(size_t)(c + 32 ) * cs];
        float4 v2 = xp[(size_t)(c + 64 ) * cs];
        float4 v3 = xp[(size_t)(c + 96 ) * cs];
        a0.x += v0.x; a0.y += v0.y; a0.z += v0.z; a0.w += v0.w;
        a1.x += v1.x; a1.y += v1.y; a1.z += v1.z; a1.w += v1.w;
        a2.x += v2.x; a2.y += v2.y; a2.z += v2.z; a2.w += v2.w;
        a3.x += v3.x; a3.y += v3.y; a3.z += v3.z; a3.w += v3.w;
    }
    float4 s;
    s.x = (a0.x + a1.x) + (a2.x + a3.x);
    s.y = (a0.y + a1.y) + (a2.y + a3.y);
    s.z = (a0.z + a1.z) + (a2.z + a3.z);
    s.w = (a0.w + a1.w) + (a2.w + a3.w);

    int r  = sp / (W / 4);
    int c4 = (sp % (W / 4)) * 4;
    // padded position: row r -> r+1, col c -> c+4 (both keep 16B alignment)
    *(float4*)(spad + (size_t)n * SPLANE + (size_t)(r + 1) * SW + (c4 + 4)) = s;
}

// ------- k2: sobel-edge + 2x2 maxpool + channel broadcast (branchless) -----
__global__ void __launch_bounds__(256) kedge_pool_bcast(const float* __restrict__ spad,
                                                        float* __restrict__ out) {
    int idx = blockIdx.x * blockDim.x + threadIdx.x;   // 0 .. N*PH*(PW/4)-1
    int n   = idx / (PH * (PW / 4));
    int r   = idx % (PH * (PW / 4));
    int ph  = r / (PW / 4);
    int pw4 = (r % (PW / 4)) * 4;

    // s-rows 2ph-1..2ph+2 -> padded rows 2ph..2ph+3
    // s-cols 2*pw4-1..2*pw4+8 -> padded cols 2*pw4+3..2*pw4+12
    const float* sp = spad + (size_t)n * SPLANE + (size_t)(2 * ph) * SW + (2 * pw4 + 3);

    float v[4][10];
#pragma unroll
    for (int i = 0; i < 4; ++i)
#pragma unroll
        for (int j = 0; j < 10; ++j)
            v[i][j] = sp[(size_t)i * SW + j];

    float pool[4];
#pragma unroll
    for (int q = 0; q < 4; ++q) {
        float m = 0.f;   // edge >= 0
#pragma unroll
        for (int a = 0; a < 2; ++a) {
#pragma unroll
            for (int b = 0; b < 2; ++b) {
                int jb = 2 * q + b;
                float p00 = v[a    ][jb], p01 = v[a    ][jb + 1], p02 = v[a    ][jb + 2];
                float p10 = v[a + 1][jb],                         p12 = v[a + 1][jb + 2];
                float p20 = v[a + 2][jb], p21 = v[a + 2][jb + 1], p22 = v[a + 2][jb + 2];
                float e0 = -p00 + p02 - 2.f * p10 + 2.f * p12 - p20 + p22;
                float e1 =  p00 + 2.f * p01 + p02 - p20 - 2.f * p21 - p22;
                float e2 = 2.f * p00 + p01 + p10 - p12 - p21 - 2.f * p22;
                float e3 = -p01 - 2.f * p02 + p10 - p12 + 2.f * p20 + p21;
                float edge = fabsf(e0) + fabsf(e1) + fabsf(e2) + fabsf(e3);
                m = fmaxf(m, edge);
            }
        }
        pool[q] = m;
    }
    float4 pv = make_float4(pool[0], pool[1], pool[2], pool[3]);

    int cbase = blockIdx.y * 16;   // gridDim.y = 8 -> 128 channels
    size_t base = (size_t)n * C * PHW + (size_t)cbase * PHW + (size_t)ph * PW + pw4;
#pragma unroll
    for (int c = 0; c < 16; ++c)
        *(float4*)(out + base + (size_t)c * PHW) = pv;
}

extern "C" void kernel_launch(void* const* d_in, const int* in_sizes, int n_in,
                              void* d_out, int out_size, void* d_ws, size_t ws_size,
                              hipStream_t stream) {
    const float* x = (const float*)d_in[0];
    float* out  = (float*)d_out;
    float* spad = (float*)d_ws;    // N*SPLANE*4 ~= 2.14 MB

    // zero the padded plane (ws is poisoned 0xAA before every launch)
    hipMemsetAsync(spad, 0, (size_t)N * SPLANE * sizeof(float), stream);

    // k1: 512 blocks, 256MB read -> 2MB padded write
    ksum_pad<<<dim3(NHW4 / 256), dim3(256), 0, stream>>>(x, spad);

    // k2: L2-resident reads, 64MB coalesced broadcast write
    kedge_pool_bcast<<<dim3((N * PH * (PW / 4)) / 256, 8), dim3(256), 0, stream>>>(spad, out);
}